// Round 13
// baseline (688.619 us; speedup 1.0000x reference)
//
#include <hip/hip_runtime.h>
#include <hip/hip_bf16.h>

typedef __hip_bfloat16 bf16;
typedef short v8s __attribute__((ext_vector_type(8)));     // 8 bf16 (4 VGPRs)
typedef float f32x4 __attribute__((ext_vector_type(4)));   // MFMA acc

#define B_  32
#define L_  144
#define D_  96
#define HW_ 64

#define WPACK_ELEMS (83*5*96*32) // packed bf16 weights

__device__ __forceinline__ unsigned short f2bf(float f) {
    union { float f; unsigned int u; } x{f};
    unsigned int r = x.u + 0x7fffu + ((x.u >> 16) & 1u);   // RNE
    return (unsigned short)(r >> 16);
}
__device__ __forceinline__ float bf2f(unsigned short u) {
    union { unsigned int u; float f; } x{(unsigned int)u << 16};
    return x.f;
}

// ---------------------------------------------------------------------------
// Weight prep: pack w1/w2/w3 (fp32, [D][L][k][k]) into A-fragment order bf16:
// wpack[((T*5+q)*96 + d)*32 + l~],  T: 0..48=7x7 taps, 49..73=5x5, 74..82=3x3,
// q = l-chunk (l = q*32+l~, zero-padded past 143).
// ---------------------------------------------------------------------------
__global__ __launch_bounds__(256) void prep_weights(
    const float* __restrict__ w1, const float* __restrict__ w2,
    const float* __restrict__ w3, unsigned short* __restrict__ wpack)
{
    int i = blockIdx.x * 256 + threadIdx.x;
    if (i >= WPACK_ELEMS) return;
    const int lt = i & 31;
    const int d  = (i >> 5) % 96;
    const int r  = (i >> 5) / 96;   // T*5 + q
    const int q  = r % 5;
    const int T  = r / 5;
    const int l  = q * 32 + lt;
    float v = 0.f;
    if (l < L_) {
        if (T < 49)      v = w3[(d * L_ + l) * 49 + T];
        else if (T < 74) v = w2[(d * L_ + l) * 25 + (T - 49)];
        else             v = w1[(d * L_ + l) * 9  + (T - 74)];
    }
    wpack[i] = f2bf(v);
}

// ---------------------------------------------------------------------------
// Single-branch MFMA conv. Register structure = round 7 (12 accs, VGPR ~52,
// 4 waves/SIMD). LDS layout = round 11 transposed conflict-free:
//   patchB[section(4)][pixel(PADN)][16B];  B-read = base + imm offsets,
//   lane (lo,hi) -> 16B-column (lo + (PADN%8)*hi) & 7: 8 lanes/column = 0
//   read conflicts. Staging = round 7's scratch-free per-element form
//   (direct 2B ds_write, NO address-taken locals — rounds 8/10/11 each
//   proved any extra per-thread state becomes ~0.5GB scratch traffic).
// MODE 0: y -> slot upper half (7x7/y3); MODE 1: y -> lower (5x5/y2);
// MODE 2: y1 + combine: add -> lower, max -> upper.
// ---------------------------------------------------------------------------
template<int KSZ, int TBASE, int MODE>
__global__ __launch_bounds__(512, 4) void conv_branch(
    const float* __restrict__ x, const unsigned short* __restrict__ wpack,
    const float* __restrict__ bb, const float* __restrict__ gg,
    const float* __restrict__ bbe, const float* __restrict__ mm,
    const float* __restrict__ vv,
    float* __restrict__ outp)
{
    constexpr int PAD  = KSZ / 2;
    constexpr int PXR  = 16 + 2 * PAD;    // patch rows/cols
    constexpr int NPIX = PXR * PXR;
    constexpr int PADN = NPIX + 2;        // PADN%8 in {2,6}: hi-sections land on distinct columns

    __shared__ __align__(16) unsigned char patchB[4 * PADN * 16];
    __shared__ float bns[96 * 2];

    const int t    = threadIdx.x;
    const int lane = t & 63;
    const int wid  = t >> 6;           // 0..7
    const int dhalf = wid >> 2;        // 0..1
    const int ptb   = (wid & 3) * 4;   // px-quad base row
    const int lo = lane & 15;
    const int hi = lane >> 4;

    const int st = blockIdx.x;
    const int h0 = (st >> 2) << 4;
    const int w0 = (st & 3) << 4;
    const int b  = blockIdx.y;

    if (t < 96) {
        const float iv = gg[t] * rsqrtf(vv[t] + 1e-5f);
        bns[t*2+0] = iv;
        bns[t*2+1] = fmaf(bb[t] - mm[t], iv, bbe[t]);
    }

    f32x4 acc[3][4];
    #pragma unroll
    for (int dt = 0; dt < 3; ++dt)
        #pragma unroll
        for (int pp = 0; pp < 4; ++pp) acc[dt][pp] = (f32x4)0.f;

    const unsigned short* wqBase = wpack + dhalf * 1536 + lo * 32 + hi * 8;
    // thread-constant B base; all tap/pp offsets are compile-time immediates
    const unsigned char* pB = patchB + (hi * PADN + ptb * PXR + lo) * 16;

    for (int q = 0; q < 5; ++q) {
        __syncthreads();
        // ---- stage chunk q (round-7 form, direct 2B LDS writes) ----
        for (int i = t; i < NPIX * 32; i += 512) {
            const int l   = i / NPIX;          // 0..31 channel-in-chunk
            const int pix = i - l * NPIX;
            const int r = pix / PXR, c = pix - r * PXR;
            const int gh = h0 - PAD + r, gw = w0 - PAD + c;
            const int lg = q * 32 + l;
            float v = 0.f;
            if (lg < L_ && (unsigned)gh < 64u && (unsigned)gw < 64u)
                v = x[(((size_t)b * L_ + lg) << 12) + (gh << 6) + gw];
            *(unsigned short*)(patchB + ((l >> 3) * PADN + pix) * 16 + (l & 7) * 2) = f2bf(v);
        }
        __syncthreads();

        const unsigned short* wq = wqBase + q * 3072;

        for (int kh = 0; kh < KSZ; ++kh) {
            #pragma unroll
            for (int kw = 0; kw < KSZ; ++kw) {
                const unsigned short* wp = wq + (TBASE + kh * KSZ + kw) * 15360;
                const v8s A0 = *(const v8s*)(wp);
                const v8s A1 = *(const v8s*)(wp + 512);
                const v8s A2 = *(const v8s*)(wp + 1024);
                v8s Bv[4];
                #pragma unroll
                for (int pp = 0; pp < 4; ++pp)
                    Bv[pp] = *(const v8s*)(pB + ((pp + kh) * PXR + kw) * 16);
                #pragma unroll
                for (int pp = 0; pp < 4; ++pp) {
                    acc[0][pp] = __builtin_amdgcn_mfma_f32_16x16x32_bf16(A0, Bv[pp], acc[0][pp], 0, 0, 0);
                    acc[1][pp] = __builtin_amdgcn_mfma_f32_16x16x32_bf16(A1, Bv[pp], acc[1][pp], 0, 0, 0);
                    acc[2][pp] = __builtin_amdgcn_mfma_f32_16x16x32_bf16(A2, Bv[pp], acc[2][pp], 0, 0, 0);
                }
            }
        }
    }

    // ---- epilogue ----
    #pragma unroll
    for (int dt = 0; dt < 3; ++dt) {
        #pragma unroll
        for (int reg = 0; reg < 4; ++reg) {
            const int d = dhalf * 48 + dt * 16 + hi * 4 + reg;
            const float iv = bns[d*2+0], cv = bns[d*2+1];
            unsigned short* pl = (unsigned short*)(outp + (((size_t)b * D_ + d) << 12));
            #pragma unroll
            for (int pp = 0; pp < 4; ++pp) {
                const float y = fmaxf(0.f, fmaf(acc[dt][pp][reg], iv, cv));
                const int idx = ((h0 + ptb + pp) << 6) + w0 + lo;
                if constexpr (MODE == 0) {
                    pl[4096 + idx] = f2bf(y);
                } else if constexpr (MODE == 1) {
                    pl[idx] = f2bf(y);
                } else {
                    const float y2 = bf2f(pl[idx]);
                    const float y3 = bf2f(pl[4096 + idx]);
                    const float av = y + y2 + y3;
                    const float mv = fmaxf(y, fmaxf(y2, y3));
                    pl[idx]        = f2bf(av);
                    pl[4096 + idx] = f2bf(mv);
                }
            }
        }
    }
}

// ---------------------------------------------------------------------------
// Kernel B: per-plane 3x3 conv over [add; max] with avg folded (unchanged).
// ---------------------------------------------------------------------------
__global__ __launch_bounds__(256) void fuse_kernel(
    const float* __restrict__ wf, float* __restrict__ out)
{
    const int p = blockIdx.x;      // plane = b*96 + d
    const int t = threadIdx.x;
    __shared__ float sa[66 * 66];
    __shared__ float sm[66 * 66];
    const bf16* base = (const bf16*)(out + ((size_t)p << 12));

    for (int i = t; i < 66 * 66; i += 256) {
        const int c = i % 66, r = i / 66;
        const int gh = r - 1, gw = c - 1;
        float va = 0.f, vm = 0.f;
        if (gh >= 0 && gh < 64 && gw >= 0 && gw < 64) {
            va = __bfloat162float(base[(gh << 6) + gw]);
            vm = __bfloat162float(base[4096 + (gh << 6) + gw]);
        }
        sa[i] = va; sm[i] = vm;
    }

    float wa[9], wm[9];
    #pragma unroll
    for (int j = 0; j < 9; ++j) {
        wa[j] = wf[j] + wf[9 + j] * (1.f / 3.f);
        wm[j] = wf[18 + j];
    }
    __syncthreads();

    float* op = out + ((size_t)p << 12);
    for (int i = t; i < 4096; i += 256) {
        const int h = i >> 6, w = i & 63;
        float acc = 0.f;
        #pragma unroll
        for (int kh = 0; kh < 3; ++kh) {
            #pragma unroll
            for (int kw = 0; kw < 3; ++kw) {
                acc = fmaf(sa[(h + kh) * 66 + (w + kw)], wa[kh * 3 + kw], acc);
                acc = fmaf(sm[(h + kh) * 66 + (w + kw)], wm[kh * 3 + kw], acc);
            }
        }
        op[i] = acc;
    }
}

extern "C" void kernel_launch(void* const* d_in, const int* in_sizes, int n_in,
                              void* d_out, int out_size, void* d_ws, size_t ws_size,
                              hipStream_t stream)
{
    const float* x   = (const float*)d_in[0];
    const float* w1  = (const float*)d_in[1];
    const float* b1  = (const float*)d_in[2];
    const float* g1  = (const float*)d_in[3];
    const float* be1 = (const float*)d_in[4];
    const float* m1  = (const float*)d_in[5];
    const float* v1  = (const float*)d_in[6];
    const float* w2  = (const float*)d_in[7];
    const float* b2  = (const float*)d_in[8];
    const float* g2  = (const float*)d_in[9];
    const float* be2 = (const float*)d_in[10];
    const float* m2  = (const float*)d_in[11];
    const float* v2  = (const float*)d_in[12];
    const float* w3  = (const float*)d_in[13];
    const float* b3  = (const float*)d_in[14];
    const float* g3  = (const float*)d_in[15];
    const float* be3 = (const float*)d_in[16];
    const float* m3  = (const float*)d_in[17];
    const float* v3  = (const float*)d_in[18];
    const float* wf  = (const float*)d_in[19];
    float* out = (float*)d_out;

    // d_ws: packed bf16 weights only (2.55 MB, proven safe rounds 4-11)
    unsigned short* wpack = (unsigned short*)d_ws;

    prep_weights<<<(WPACK_ELEMS + 255) / 256, 256, 0, stream>>>(w1, w2, w3, wpack);

    dim3 gridA(16, B_);   // 16 spatial tiles x 32 batch
    conv_branch<7, 0, 0><<<gridA, 512, 0, stream>>>(x, wpack, b3, g3, be3, m3, v3, out);
    conv_branch<5, 49, 1><<<gridA, 512, 0, stream>>>(x, wpack, b2, g2, be2, m2, v2, out);
    conv_branch<3, 74, 2><<<gridA, 512, 0, stream>>>(x, wpack, b1, g1, be1, m1, v1, out);

    fuse_kernel<<<B_ * D_, 256, 0, stream>>>(wf, out);
}

// Round 14
// 479.074 us; speedup vs baseline: 1.4374x; 1.4374x over previous
//
#include <hip/hip_runtime.h>
#include <hip/hip_bf16.h>

typedef __hip_bfloat16 bf16;
typedef short v8s __attribute__((ext_vector_type(8)));     // 8 bf16 (4 VGPRs)
typedef float f32x4 __attribute__((ext_vector_type(4)));   // MFMA acc

#define B_  32
#define L_  144
#define D_  96
#define HW_ 64

#define PIXSTRIDE 80             // 32 l * 2B = 64B data + 16B pad (round-7 layout)
#define WPACK_ELEMS (83*5*96*32) // packed bf16 weights

__device__ __forceinline__ unsigned short f2bf(float f) {
    union { float f; unsigned int u; } x{f};
    unsigned int r = x.u + 0x7fffu + ((x.u >> 16) & 1u);   // RNE
    return (unsigned short)(r >> 16);
}
__device__ __forceinline__ float bf2f(unsigned short u) {
    union { unsigned int u; float f; } x{(unsigned int)u << 16};
    return x.f;
}

// ---------------------------------------------------------------------------
// Weight prep: pack w1/w2/w3 (fp32, [D][L][k][k]) into A-fragment order bf16:
// wpack[((T*5+q)*96 + d)*32 + l~],  T: 0..48=7x7 taps, 49..73=5x5, 74..82=3x3,
// q = l-chunk (l = q*32+l~, zero-padded past 143).
// ---------------------------------------------------------------------------
__global__ __launch_bounds__(256) void prep_weights(
    const float* __restrict__ w1, const float* __restrict__ w2,
    const float* __restrict__ w3, unsigned short* __restrict__ wpack)
{
    int i = blockIdx.x * 256 + threadIdx.x;
    if (i >= WPACK_ELEMS) return;
    const int lt = i & 31;
    const int d  = (i >> 5) % 96;
    const int r  = (i >> 5) / 96;   // T*5 + q
    const int q  = r % 5;
    const int T  = r / 5;
    const int l  = q * 32 + lt;
    float v = 0.f;
    if (l < L_) {
        if (T < 49)      v = w3[(d * L_ + l) * 49 + T];
        else if (T < 74) v = w2[(d * L_ + l) * 25 + (T - 49)];
        else             v = w1[(d * L_ + l) * 9  + (T - 74)];
    }
    wpack[i] = f2bf(v);
}

// ---------------------------------------------------------------------------
// Single-branch MFMA conv — EXACT round-7 structure (12 accs, VGPR ~52,
// 4 waves/SIMD, [pixel][32ch] stride-80 LDS, runtime-kh B addressing) with
// ONE change: the staging loop. Thread owns one pixel (div/mod hoisted out
// of the q loop); 16 channel-pair iterations of {2 coalesced f32 loads ->
// one u32 ds_write} built with scalar bit-ops (no vector locals: rounds
// 8/10/11 proved any extra per-thread aggregate state becomes ~0.5 GB
// scratch traffic; round 13 proved immediate-offset restructuring does too).
// MODE 0: y -> slot upper half (7x7/y3); MODE 1: y -> lower (5x5/y2);
// MODE 2: y1 + combine: add -> lower, max -> upper.
// ---------------------------------------------------------------------------
template<int KSZ, int TBASE, int MODE>
__global__ __launch_bounds__(512, 4) void conv_branch(
    const float* __restrict__ x, const unsigned short* __restrict__ wpack,
    const float* __restrict__ bb, const float* __restrict__ gg,
    const float* __restrict__ bbe, const float* __restrict__ mm,
    const float* __restrict__ vv,
    float* __restrict__ outp)
{
    constexpr int PAD  = KSZ / 2;
    constexpr int PXR  = 16 + 2 * PAD;    // patch rows/cols
    constexpr int NPIX = PXR * PXR;

    __shared__ __align__(16) unsigned char patchB[NPIX * PIXSTRIDE];
    __shared__ float bns[96 * 2];

    const int t    = threadIdx.x;
    const int lane = t & 63;
    const int wid  = t >> 6;           // 0..7
    const int dhalf = wid >> 2;        // 0..1
    const int ptb   = (wid & 3) * 4;   // px-quad base row
    const int lo = lane & 15;
    const int hi = lane >> 4;

    const int st = blockIdx.x;
    const int h0 = (st >> 2) << 4;
    const int w0 = (st & 3) << 4;
    const int b  = blockIdx.y;

    const int laneBoff = lo * PIXSTRIDE + hi * 16;
    const int laneAoff = lo * 32 + hi * 8;

    // ---- staging precompute: thread owns pixel t (div/mod ONCE) ----
    const bool pvalid = (t < NPIX);
    const int pr = t / PXR, pc = t - pr * PXR;
    const int gh = h0 - PAD + pr, gw = w0 - PAD + pc;
    const bool inb = pvalid && ((unsigned)gh < 64u) && ((unsigned)gw < 64u);
    const float* xb = x + (((size_t)b * L_) << 12);
    const long goff = (long)(gh << 6) + gw;

    if (t < 96) {
        const float iv = gg[t] * rsqrtf(vv[t] + 1e-5f);
        bns[t*2+0] = iv;
        bns[t*2+1] = fmaf(bb[t] - mm[t], iv, bbe[t]);
    }

    f32x4 acc[3][4];
    #pragma unroll
    for (int dt = 0; dt < 3; ++dt)
        #pragma unroll
        for (int pp = 0; pp < 4; ++pp) acc[dt][pp] = (f32x4)0.f;

    const unsigned short* wqBase = wpack + dhalf * 1536 + laneAoff;

    for (int q = 0; q < 5; ++q) {
        __syncthreads();
        // ---- stage chunk q: 16 channel-pair iters, scalar u32 writes ----
        if (pvalid) {
            #pragma unroll 4
            for (int l = 0; l < 32; l += 2) {
                const int lg = q * 32 + l;
                float v0 = 0.f, v1 = 0.f;
                if (inb) {
                    if (lg < L_)     v0 = xb[(long)lg * 4096 + goff];
                    if (lg + 1 < L_) v1 = xb[(long)(lg + 1) * 4096 + goff];
                }
                *(unsigned int*)(patchB + t * PIXSTRIDE + l * 2) =
                    (unsigned int)f2bf(v0) | ((unsigned int)f2bf(v1) << 16);
            }
        }
        __syncthreads();

        const unsigned short* wq = wqBase + q * 3072;

        for (int kh = 0; kh < KSZ; ++kh) {
            const int rb0 = (ptb + kh) * PXR;
            #pragma unroll
            for (int kw = 0; kw < KSZ; ++kw) {
                const unsigned short* wp = wq + (TBASE + kh * KSZ + kw) * 15360;
                const v8s A0 = *(const v8s*)(wp);
                const v8s A1 = *(const v8s*)(wp + 512);
                const v8s A2 = *(const v8s*)(wp + 1024);
                v8s Bv[4];
                #pragma unroll
                for (int pp = 0; pp < 4; ++pp)
                    Bv[pp] = *(const v8s*)(patchB + (rb0 + pp * PXR + kw) * PIXSTRIDE + laneBoff);
                #pragma unroll
                for (int pp = 0; pp < 4; ++pp) {
                    acc[0][pp] = __builtin_amdgcn_mfma_f32_16x16x32_bf16(A0, Bv[pp], acc[0][pp], 0, 0, 0);
                    acc[1][pp] = __builtin_amdgcn_mfma_f32_16x16x32_bf16(A1, Bv[pp], acc[1][pp], 0, 0, 0);
                    acc[2][pp] = __builtin_amdgcn_mfma_f32_16x16x32_bf16(A2, Bv[pp], acc[2][pp], 0, 0, 0);
                }
            }
        }
    }

    // ---- epilogue (round-7 verbatim) ----
    #pragma unroll
    for (int dt = 0; dt < 3; ++dt) {
        #pragma unroll
        for (int reg = 0; reg < 4; ++reg) {
            const int d = dhalf * 48 + dt * 16 + hi * 4 + reg;
            const float iv = bns[d*2+0], cv = bns[d*2+1];
            unsigned short* pl = (unsigned short*)(outp + (((size_t)b * D_ + d) << 12));
            #pragma unroll
            for (int pp = 0; pp < 4; ++pp) {
                const float y = fmaxf(0.f, fmaf(acc[dt][pp][reg], iv, cv));
                const int idx = ((h0 + ptb + pp) << 6) + w0 + lo;
                if constexpr (MODE == 0) {
                    pl[4096 + idx] = f2bf(y);
                } else if constexpr (MODE == 1) {
                    pl[idx] = f2bf(y);
                } else {
                    const float y2 = bf2f(pl[idx]);
                    const float y3 = bf2f(pl[4096 + idx]);
                    const float av = y + y2 + y3;
                    const float mv = fmaxf(y, fmaxf(y2, y3));
                    pl[idx]        = f2bf(av);
                    pl[4096 + idx] = f2bf(mv);
                }
            }
        }
    }
}

// ---------------------------------------------------------------------------
// Kernel B: per-plane 3x3 conv over [add; max] with avg folded (unchanged).
// ---------------------------------------------------------------------------
__global__ __launch_bounds__(256) void fuse_kernel(
    const float* __restrict__ wf, float* __restrict__ out)
{
    const int p = blockIdx.x;      // plane = b*96 + d
    const int t = threadIdx.x;
    __shared__ float sa[66 * 66];
    __shared__ float sm[66 * 66];
    const bf16* base = (const bf16*)(out + ((size_t)p << 12));

    for (int i = t; i < 66 * 66; i += 256) {
        const int c = i % 66, r = i / 66;
        const int gh = r - 1, gw = c - 1;
        float va = 0.f, vm = 0.f;
        if (gh >= 0 && gh < 64 && gw >= 0 && gw < 64) {
            va = __bfloat162float(base[(gh << 6) + gw]);
            vm = __bfloat162float(base[4096 + (gh << 6) + gw]);
        }
        sa[i] = va; sm[i] = vm;
    }

    float wa[9], wm[9];
    #pragma unroll
    for (int j = 0; j < 9; ++j) {
        wa[j] = wf[j] + wf[9 + j] * (1.f / 3.f);
        wm[j] = wf[18 + j];
    }
    __syncthreads();

    float* op = out + ((size_t)p << 12);
    for (int i = t; i < 4096; i += 256) {
        const int h = i >> 6, w = i & 63;
        float acc = 0.f;
        #pragma unroll
        for (int kh = 0; kh < 3; ++kh) {
            #pragma unroll
            for (int kw = 0; kw < 3; ++kw) {
                acc = fmaf(sa[(h + kh) * 66 + (w + kw)], wa[kh * 3 + kw], acc);
                acc = fmaf(sm[(h + kh) * 66 + (w + kw)], wm[kh * 3 + kw], acc);
            }
        }
        op[i] = acc;
    }
}

extern "C" void kernel_launch(void* const* d_in, const int* in_sizes, int n_in,
                              void* d_out, int out_size, void* d_ws, size_t ws_size,
                              hipStream_t stream)
{
    const float* x   = (const float*)d_in[0];
    const float* w1  = (const float*)d_in[1];
    const float* b1  = (const float*)d_in[2];
    const float* g1  = (const float*)d_in[3];
    const float* be1 = (const float*)d_in[4];
    const float* m1  = (const float*)d_in[5];
    const float* v1  = (const float*)d_in[6];
    const float* w2  = (const float*)d_in[7];
    const float* b2  = (const float*)d_in[8];
    const float* g2  = (const float*)d_in[9];
    const float* be2 = (const float*)d_in[10];
    const float* m2  = (const float*)d_in[11];
    const float* v2  = (const float*)d_in[12];
    const float* w3  = (const float*)d_in[13];
    const float* b3  = (const float*)d_in[14];
    const float* g3  = (const float*)d_in[15];
    const float* be3 = (const float*)d_in[16];
    const float* m3  = (const float*)d_in[17];
    const float* v3  = (const float*)d_in[18];
    const float* wf  = (const float*)d_in[19];
    float* out = (float*)d_out;

    // d_ws: packed bf16 weights only (2.55 MB, proven safe rounds 4-13)
    unsigned short* wpack = (unsigned short*)d_ws;

    prep_weights<<<(WPACK_ELEMS + 255) / 256, 256, 0, stream>>>(w1, w2, w3, wpack);

    dim3 gridA(16, B_);   // 16 spatial tiles x 32 batch
    conv_branch<7, 0, 0><<<gridA, 512, 0, stream>>>(x, wpack, b3, g3, be3, m3, v3, out);
    conv_branch<5, 49, 1><<<gridA, 512, 0, stream>>>(x, wpack, b2, g2, be2, m2, v2, out);
    conv_branch<3, 74, 2><<<gridA, 512, 0, stream>>>(x, wpack, b1, g1, be1, m1, v1, out);

    fuse_kernel<<<B_ * D_, 256, 0, stream>>>(wf, out);
}

// Round 18
// 418.293 us; speedup vs baseline: 1.6463x; 1.1453x over previous
//
#include <hip/hip_runtime.h>
#include <hip/hip_bf16.h>

typedef __hip_bfloat16 bf16;
typedef short v8s __attribute__((ext_vector_type(8)));     // 8 bf16 (4 VGPRs)
typedef float f32x4 __attribute__((ext_vector_type(4)));   // MFMA acc

#define B_  32
#define L_  144
#define D_  96
#define HW_ 64

#define PIXSTRIDE 80             // 32 l * 2B = 64B data + 16B pad (round-7/14 layout)
#define WPACK_ELEMS (83*5*96*32) // packed bf16 weights
#define ABUF_HALF 18432          // 3 taps * 6KB A per tap

__device__ __forceinline__ unsigned short f2bf(float f) {
    union { float f; unsigned int u; } x{f};
    unsigned int r = x.u + 0x7fffu + ((x.u >> 16) & 1u);   // RNE
    return (unsigned short)(r >> 16);
}
__device__ __forceinline__ float bf2f(unsigned short u) {
    union { unsigned int u; float f; } x{(unsigned int)u << 16};
    return x.f;
}

// ---------------------------------------------------------------------------
// Weight prep: pack w1/w2/w3 (fp32, [D][L][k][k]) into A-fragment order bf16:
// wpack[((T*5+q)*96 + d)*32 + l~],  T: 0..48=7x7 taps, 49..73=5x5, 74..82=3x3,
// q = l-chunk (l = q*32+l~, zero-padded past 143).
// ---------------------------------------------------------------------------
__global__ __launch_bounds__(256) void prep_weights(
    const float* __restrict__ w1, const float* __restrict__ w2,
    const float* __restrict__ w3, unsigned short* __restrict__ wpack)
{
    int i = blockIdx.x * 256 + threadIdx.x;
    if (i >= WPACK_ELEMS) return;
    const int lt = i & 31;
    const int d  = (i >> 5) % 96;
    const int r  = (i >> 5) / 96;   // T*5 + q
    const int q  = r % 5;
    const int T  = r / 5;
    const int l  = q * 32 + lt;
    float v = 0.f;
    if (l < L_) {
        if (T < 49)      v = w3[(d * L_ + l) * 49 + T];
        else if (T < 74) v = w2[(d * L_ + l) * 25 + (T - 49)];
        else             v = w1[(d * L_ + l) * 9  + (T - 74)];
    }
    wpack[i] = f2bf(v);
}

// ---------------------------------------------------------------------------
// Single-branch MFMA conv — round-14 structure (12 accs, 4 waves/SIMD,
// [pixel][32ch] stride-80 patch, per-pixel staging) + A-weights staged into
// LDS via global_load_lds in double-buffered 3-tap groups:
//   Abuf[2][3 taps][6 chunks of 1KB];  chunk c=(tap*6 + dhalf*3 + dt) holds
//   the 512-elem A block PRE-SWIZZLED at the global source so reader lane l
//   finds its 16B frag at chunk_base + l*16 (conflict-free columns l%8).
// Issue group tg+1's DMA before computing group tg; __syncthreads' vmcnt(0)
// drain lands after ~36 MFMAs of cover (m97 pattern). Removes the 245
// sequential per-wave A L2 round-trips that capped round 14 at 34% MfmaUtil.
// MODE 0: y -> slot upper half (7x7/y3); MODE 1: y -> lower (5x5/y2);
// MODE 2: y1 + combine: add -> lower, max -> upper.
// ---------------------------------------------------------------------------
template<int KSZ, int TBASE, int MODE>
__global__ __launch_bounds__(512, 4) void conv_branch(
    const float* __restrict__ x, const unsigned short* __restrict__ wpack,
    const float* __restrict__ bb, const float* __restrict__ gg,
    const float* __restrict__ bbe, const float* __restrict__ mm,
    const float* __restrict__ vv,
    float* __restrict__ outp)
{
    constexpr int PAD  = KSZ / 2;
    constexpr int PXR  = 16 + 2 * PAD;    // patch rows/cols
    constexpr int NPIX = PXR * PXR;
    constexpr int NT   = KSZ * KSZ;       // taps
    constexpr int NG   = (NT + 2) / 3;    // 3-tap groups

    __shared__ __align__(16) unsigned char patchB[NPIX * PIXSTRIDE];
    __shared__ __align__(16) unsigned char AbufRaw[2 * ABUF_HALF];
    __shared__ float bns[96 * 2];

    const int t    = threadIdx.x;
    const int lane = t & 63;
    const int wid  = t >> 6;           // 0..7
    const int dhalf = wid >> 2;        // 0..1
    const int ptb   = (wid & 3) * 4;   // px-quad base row
    const int lo = lane & 15;
    const int hi = lane >> 4;

    const int st = blockIdx.x;
    const int h0 = (st >> 2) << 4;
    const int w0 = (st & 3) << 4;
    const int b  = blockIdx.y;

    const int laneBoff = lo * PIXSTRIDE + hi * 16;

    // staging precompute: thread owns pixel t (div/mod once)
    const bool pvalid = (t < NPIX);
    const int pr = t / PXR, pc = t - pr * PXR;
    const int gh = h0 - PAD + pr, gw = w0 - PAD + pc;
    const bool inb = pvalid && ((unsigned)gh < 64u) && ((unsigned)gw < 64u);
    const float* xb = x + (((size_t)b * L_) << 12);
    const long goff = (long)(gh << 6) + gw;

    if (t < 96) {
        const float iv = gg[t] * rsqrtf(vv[t] + 1e-5f);
        bns[t*2+0] = iv;
        bns[t*2+1] = fmaf(bb[t] - mm[t], iv, bbe[t]);
    }

    f32x4 acc[3][4];
    #pragma unroll
    for (int dt = 0; dt < 3; ++dt)
        #pragma unroll
        for (int pp = 0; pp < 4; ++pp) acc[dt][pp] = (f32x4)0.f;

    // per-lane pre-swizzled A source offset (elems): lane's frag within a 512-elem block
    const int laneAsrc = (lane & 15) * 32 + (lane >> 4) * 8;

    for (int q = 0; q < 5; ++q) {
        // ---- stage patch chunk q (round-14 verbatim) ----
        if (pvalid) {
            #pragma unroll 4
            for (int l = 0; l < 32; l += 2) {
                const int lg = q * 32 + l;
                float v0 = 0.f, v1 = 0.f;
                if (inb) {
                    if (lg < L_)     v0 = xb[(long)lg * 4096 + goff];
                    if (lg + 1 < L_) v1 = xb[(long)(lg + 1) * 4096 + goff];
                }
                *(unsigned int*)(patchB + t * PIXSTRIDE + l * 2) =
                    (unsigned int)f2bf(v0) | ((unsigned int)f2bf(v1) << 16);
            }
        }

        // ---- DMA-stage A group: chunk c = tap*6 + (dhalf*3+dt), 1KB each ----
        auto stageA = [&](int tapLo, int bufOff) {
            const int rem  = NT - tapLo;
            const int nch  = (rem < 3 ? rem : 3) * 6;
            const unsigned short* gq = wpack
                + (size_t)(TBASE + tapLo) * 15360 + (size_t)q * 3072 + laneAsrc;
            for (int c = wid; c < nch; c += 8) {
                const int tapIdx = c / 6;
                const int r = c - tapIdx * 6;
                const unsigned short* g = gq + (size_t)tapIdx * 15360 + r * 512;
                __builtin_amdgcn_global_load_lds(
                    (const __attribute__((address_space(1))) unsigned int*)g,
                    (__attribute__((address_space(3))) unsigned int*)(AbufRaw + bufOff + c * 1024),
                    16, 0, 0);
            }
        };

        stageA(0, 0);          // prologue: group 0 -> buf 0
        __syncthreads();       // patch + A group 0 visible

        for (int tg = 0; tg < NG; ++tg) {
            if (tg + 1 < NG) stageA((tg + 1) * 3, ((tg + 1) & 1) * ABUF_HALF);

            // ---- compute group tg from buf[tg&1] ----
            const unsigned char* Ab = AbufRaw + (tg & 1) * ABUF_HALF;
            const int tapLo = tg * 3;
            const int rem = NT - tapLo;
            const int ntap = rem < 3 ? rem : 3;
            #pragma unroll 1
            for (int ti = 0; ti < ntap; ++ti) {
                const int tt = tapLo + ti;
                const int kh = tt / KSZ, kw = tt - kh * KSZ;
                const unsigned char* Abase = Ab + (ti * 6 + dhalf * 3) * 1024 + lane * 16;
                const v8s A0 = *(const v8s*)(Abase);
                const v8s A1 = *(const v8s*)(Abase + 1024);
                const v8s A2 = *(const v8s*)(Abase + 2048);
                const int rb0 = (ptb + kh) * PXR;
                v8s Bv[4];
                #pragma unroll
                for (int pp = 0; pp < 4; ++pp)
                    Bv[pp] = *(const v8s*)(patchB + (rb0 + pp * PXR + kw) * PIXSTRIDE + laneBoff);
                #pragma unroll
                for (int pp = 0; pp < 4; ++pp) {
                    acc[0][pp] = __builtin_amdgcn_mfma_f32_16x16x32_bf16(A0, Bv[pp], acc[0][pp], 0, 0, 0);
                    acc[1][pp] = __builtin_amdgcn_mfma_f32_16x16x32_bf16(A1, Bv[pp], acc[1][pp], 0, 0, 0);
                    acc[2][pp] = __builtin_amdgcn_mfma_f32_16x16x32_bf16(A2, Bv[pp], acc[2][pp], 0, 0, 0);
                }
            }
            __syncthreads();   // drains next group's DMA (covered by the 36 MFMAs above)
        }
    }

    // ---- epilogue (round-7/14 verbatim) ----
    #pragma unroll
    for (int dt = 0; dt < 3; ++dt) {
        #pragma unroll
        for (int reg = 0; reg < 4; ++reg) {
            const int d = dhalf * 48 + dt * 16 + hi * 4 + reg;
            const float iv = bns[d*2+0], cv = bns[d*2+1];
            unsigned short* pl = (unsigned short*)(outp + (((size_t)b * D_ + d) << 12));
            #pragma unroll
            for (int pp = 0; pp < 4; ++pp) {
                const float y = fmaxf(0.f, fmaf(acc[dt][pp][reg], iv, cv));
                const int idx = ((h0 + ptb + pp) << 6) + w0 + lo;
                if constexpr (MODE == 0) {
                    pl[4096 + idx] = f2bf(y);
                } else if constexpr (MODE == 1) {
                    pl[idx] = f2bf(y);
                } else {
                    const float y2 = bf2f(pl[idx]);
                    const float y3 = bf2f(pl[4096 + idx]);
                    const float av = y + y2 + y3;
                    const float mv = fmaxf(y, fmaxf(y2, y3));
                    pl[idx]        = f2bf(av);
                    pl[4096 + idx] = f2bf(mv);
                }
            }
        }
    }
}

// ---------------------------------------------------------------------------
// Kernel B: per-plane 3x3 conv over [add; max] with avg folded (unchanged).
// ---------------------------------------------------------------------------
__global__ __launch_bounds__(256) void fuse_kernel(
    const float* __restrict__ wf, float* __restrict__ out)
{
    const int p = blockIdx.x;      // plane = b*96 + d
    const int t = threadIdx.x;
    __shared__ float sa[66 * 66];
    __shared__ float sm[66 * 66];
    const bf16* base = (const bf16*)(out + ((size_t)p << 12));

    for (int i = t; i < 66 * 66; i += 256) {
        const int c = i % 66, r = i / 66;
        const int gh = r - 1, gw = c - 1;
        float va = 0.f, vm = 0.f;
        if (gh >= 0 && gh < 64 && gw >= 0 && gw < 64) {
            va = __bfloat162float(base[(gh << 6) + gw]);
            vm = __bfloat162float(base[4096 + (gh << 6) + gw]);
        }
        sa[i] = va; sm[i] = vm;
    }

    float wa[9], wm[9];
    #pragma unroll
    for (int j = 0; j < 9; ++j) {
        wa[j] = wf[j] + wf[9 + j] * (1.f / 3.f);
        wm[j] = wf[18 + j];
    }
    __syncthreads();

    float* op = out + ((size_t)p << 12);
    for (int i = t; i < 4096; i += 256) {
        const int h = i >> 6, w = i & 63;
        float acc = 0.f;
        #pragma unroll
        for (int kh = 0; kh < 3; ++kh) {
            #pragma unroll
            for (int kw = 0; kw < 3; ++kw) {
                acc = fmaf(sa[(h + kh) * 66 + (w + kw)], wa[kh * 3 + kw], acc);
                acc = fmaf(sm[(h + kh) * 66 + (w + kw)], wm[kh * 3 + kw], acc);
            }
        }
        op[i] = acc;
    }
}

extern "C" void kernel_launch(void* const* d_in, const int* in_sizes, int n_in,
                              void* d_out, int out_size, void* d_ws, size_t ws_size,
                              hipStream_t stream)
{
    const float* x   = (const float*)d_in[0];
    const float* w1  = (const float*)d_in[1];
    const float* b1  = (const float*)d_in[2];
    const float* g1  = (const float*)d_in[3];
    const float* be1 = (const float*)d_in[4];
    const float* m1  = (const float*)d_in[5];
    const float* v1  = (const float*)d_in[6];
    const float* w2  = (const float*)d_in[7];
    const float* b2  = (const float*)d_in[8];
    const float* g2  = (const float*)d_in[9];
    const float* be2 = (const float*)d_in[10];
    const float* m2  = (const float*)d_in[11];
    const float* v2  = (const float*)d_in[12];
    const float* w3  = (const float*)d_in[13];
    const float* b3  = (const float*)d_in[14];
    const float* g3  = (const float*)d_in[15];
    const float* be3 = (const float*)d_in[16];
    const float* m3  = (const float*)d_in[17];
    const float* v3  = (const float*)d_in[18];
    const float* wf  = (const float*)d_in[19];
    float* out = (float*)d_out;

    // d_ws: packed bf16 weights only (2.55 MB, proven safe rounds 4-14)
    unsigned short* wpack = (unsigned short*)d_ws;

    prep_weights<<<(WPACK_ELEMS + 255) / 256, 256, 0, stream>>>(w1, w2, w3, wpack);

    dim3 gridA(16, B_);   // 16 spatial tiles x 32 batch
    conv_branch<7, 0, 0><<<gridA, 512, 0, stream>>>(x, wpack, b3, g3, be3, m3, v3, out);
    conv_branch<5, 49, 1><<<gridA, 512, 0, stream>>>(x, wpack, b2, g2, be2, m2, v2, out);
    conv_branch<3, 74, 2><<<gridA, 512, 0, stream>>>(x, wpack, b1, g1, be1, m1, v1, out);

    fuse_kernel<<<B_ * D_, 256, 0, stream>>>(wf, out);
}

// Round 19
// 397.451 us; speedup vs baseline: 1.7326x; 1.0524x over previous
//
#include <hip/hip_runtime.h>
#include <hip/hip_bf16.h>

typedef __hip_bfloat16 bf16;
typedef short v8s __attribute__((ext_vector_type(8)));     // 8 bf16 (4 VGPRs)
typedef float f32x4 __attribute__((ext_vector_type(4)));   // MFMA acc
typedef unsigned int u32x4 __attribute__((ext_vector_type(4)));

#define B_  32
#define L_  144
#define D_  96
#define HW_ 64

#define PIXSTRIDE 80             // 32 l * 2B = 64B data + 16B pad (round-7/14 layout)
#define WPACK_ELEMS (83*5*96*32) // packed bf16 weights
#define ABUF_HALF 18432          // 3 taps * 6KB A per tap

__device__ __forceinline__ unsigned short f2bf(float f) {
    union { float f; unsigned int u; } x{f};
    unsigned int r = x.u + 0x7fffu + ((x.u >> 16) & 1u);   // RNE
    return (unsigned short)(r >> 16);
}
__device__ __forceinline__ float bf2f(unsigned short u) {
    union { unsigned int u; float f; } x{(unsigned int)u << 16};
    return x.f;
}

// ---------------------------------------------------------------------------
// Weight prep: pack w1/w2/w3 (fp32, [D][L][k][k]) into A-fragment order bf16:
// wpack[((T*5+q)*96 + d)*32 + l~],  T: 0..48=7x7 taps, 49..73=5x5, 74..82=3x3,
// q = l-chunk (l = q*32+l~, zero-padded past 143).
// ---------------------------------------------------------------------------
__global__ __launch_bounds__(256) void prep_weights(
    const float* __restrict__ w1, const float* __restrict__ w2,
    const float* __restrict__ w3, unsigned short* __restrict__ wpack)
{
    int i = blockIdx.x * 256 + threadIdx.x;
    if (i >= WPACK_ELEMS) return;
    const int lt = i & 31;
    const int d  = (i >> 5) % 96;
    const int r  = (i >> 5) / 96;   // T*5 + q
    const int q  = r % 5;
    const int T  = r / 5;
    const int l  = q * 32 + lt;
    float v = 0.f;
    if (l < L_) {
        if (T < 49)      v = w3[(d * L_ + l) * 49 + T];
        else if (T < 74) v = w2[(d * L_ + l) * 25 + (T - 49)];
        else             v = w1[(d * L_ + l) * 9  + (T - 74)];
    }
    wpack[i] = f2bf(v);
}

// ---------------------------------------------------------------------------
// Single-branch MFMA conv — round-18 structure (12 accs, 4 waves/SIMD,
// [pixel][32ch] stride-80 patch, A-weights via double-buffered 3-tap-group
// global_load_lds) with ONE change: patch staging writes are ds_write_b128
// (4 per chunk instead of 16 u32 writes). Round-18 counters showed the
// 1.79e7 bank-conflict cycles are ENTIRELY the stride-80 u32 staging writes
// (8-way: lanes {0,8,16..} same bank); b128 packs 8 channels per write ->
// ~4x fewer conflict events + 4x fewer LDS-write instructions. u32x4 built
// with braced init from named scalars (unconditional construction — the
// SROA-safe pattern; rounds 8/10/11/13 proved conditional/element-wise
// aggregate construction becomes ~0.5 GB scratch traffic).
// MODE 0: y -> slot upper half (7x7/y3); MODE 1: y -> lower (5x5/y2);
// MODE 2: y1 + combine: add -> lower, max -> upper.
// ---------------------------------------------------------------------------
template<int KSZ, int TBASE, int MODE>
__global__ __launch_bounds__(512, 4) void conv_branch(
    const float* __restrict__ x, const unsigned short* __restrict__ wpack,
    const float* __restrict__ bb, const float* __restrict__ gg,
    const float* __restrict__ bbe, const float* __restrict__ mm,
    const float* __restrict__ vv,
    float* __restrict__ outp)
{
    constexpr int PAD  = KSZ / 2;
    constexpr int PXR  = 16 + 2 * PAD;    // patch rows/cols
    constexpr int NPIX = PXR * PXR;
    constexpr int NT   = KSZ * KSZ;       // taps
    constexpr int NG   = (NT + 2) / 3;    // 3-tap groups

    __shared__ __align__(16) unsigned char patchB[NPIX * PIXSTRIDE];
    __shared__ __align__(16) unsigned char AbufRaw[2 * ABUF_HALF];
    __shared__ float bns[96 * 2];

    const int t    = threadIdx.x;
    const int lane = t & 63;
    const int wid  = t >> 6;           // 0..7
    const int dhalf = wid >> 2;        // 0..1
    const int ptb   = (wid & 3) * 4;   // px-quad base row
    const int lo = lane & 15;
    const int hi = lane >> 4;

    const int st = blockIdx.x;
    const int h0 = (st >> 2) << 4;
    const int w0 = (st & 3) << 4;
    const int b  = blockIdx.y;

    const int laneBoff = lo * PIXSTRIDE + hi * 16;

    // staging precompute: thread owns pixel t (div/mod once)
    const bool pvalid = (t < NPIX);
    const int pr = t / PXR, pc = t - pr * PXR;
    const int gh = h0 - PAD + pr, gw = w0 - PAD + pc;
    const bool inb = pvalid && ((unsigned)gh < 64u) && ((unsigned)gw < 64u);
    const float* xb = x + (((size_t)b * L_) << 12);
    const long goff = (long)(gh << 6) + gw;

    if (t < 96) {
        const float iv = gg[t] * rsqrtf(vv[t] + 1e-5f);
        bns[t*2+0] = iv;
        bns[t*2+1] = fmaf(bb[t] - mm[t], iv, bbe[t]);
    }

    f32x4 acc[3][4];
    #pragma unroll
    for (int dt = 0; dt < 3; ++dt)
        #pragma unroll
        for (int pp = 0; pp < 4; ++pp) acc[dt][pp] = (f32x4)0.f;

    // per-lane pre-swizzled A source offset (elems): lane's frag within a 512-elem block
    const int laneAsrc = (lane & 15) * 32 + (lane >> 4) * 8;

    for (int q = 0; q < 5; ++q) {
        // ---- stage patch chunk q: 4x ds_write_b128 (8 channels each) ----
        if (pvalid) {
            if (q * 32 + 31 < L_) {            // chunks 0..3: all channels valid
                #pragma unroll
                for (int l0 = 0; l0 < 32; l0 += 8) {
                    const long gbase = (long)(q * 32 + l0) * 4096 + goff;
                    const float f0 = inb ? xb[gbase]           : 0.f;
                    const float f1 = inb ? xb[gbase + 4096]    : 0.f;
                    const float f2 = inb ? xb[gbase + 2*4096]  : 0.f;
                    const float f3 = inb ? xb[gbase + 3*4096]  : 0.f;
                    const float f4 = inb ? xb[gbase + 4*4096]  : 0.f;
                    const float f5 = inb ? xb[gbase + 5*4096]  : 0.f;
                    const float f6 = inb ? xb[gbase + 6*4096]  : 0.f;
                    const float f7 = inb ? xb[gbase + 7*4096]  : 0.f;
                    const unsigned int a0 = (unsigned int)f2bf(f0) | ((unsigned int)f2bf(f1) << 16);
                    const unsigned int a1 = (unsigned int)f2bf(f2) | ((unsigned int)f2bf(f3) << 16);
                    const unsigned int a2 = (unsigned int)f2bf(f4) | ((unsigned int)f2bf(f5) << 16);
                    const unsigned int a3 = (unsigned int)f2bf(f6) | ((unsigned int)f2bf(f7) << 16);
                    const u32x4 v = {a0, a1, a2, a3};
                    *(u32x4*)(patchB + t * PIXSTRIDE + l0 * 2) = v;
                }
            } else {                           // chunk 4: channels 128..159, guard >143
                #pragma unroll
                for (int l0 = 0; l0 < 32; l0 += 8) {
                    const int lg = q * 32 + l0;
                    const long gbase = (long)lg * 4096 + goff;
                    const float f0 = (inb && lg + 0 < L_) ? xb[gbase]          : 0.f;
                    const float f1 = (inb && lg + 1 < L_) ? xb[gbase + 4096]   : 0.f;
                    const float f2 = (inb && lg + 2 < L_) ? xb[gbase + 2*4096] : 0.f;
                    const float f3 = (inb && lg + 3 < L_) ? xb[gbase + 3*4096] : 0.f;
                    const float f4 = (inb && lg + 4 < L_) ? xb[gbase + 4*4096] : 0.f;
                    const float f5 = (inb && lg + 5 < L_) ? xb[gbase + 5*4096] : 0.f;
                    const float f6 = (inb && lg + 6 < L_) ? xb[gbase + 6*4096] : 0.f;
                    const float f7 = (inb && lg + 7 < L_) ? xb[gbase + 7*4096] : 0.f;
                    const unsigned int a0 = (unsigned int)f2bf(f0) | ((unsigned int)f2bf(f1) << 16);
                    const unsigned int a1 = (unsigned int)f2bf(f2) | ((unsigned int)f2bf(f3) << 16);
                    const unsigned int a2 = (unsigned int)f2bf(f4) | ((unsigned int)f2bf(f5) << 16);
                    const unsigned int a3 = (unsigned int)f2bf(f6) | ((unsigned int)f2bf(f7) << 16);
                    const u32x4 v = {a0, a1, a2, a3};
                    *(u32x4*)(patchB + t * PIXSTRIDE + l0 * 2) = v;
                }
            }
        }

        // ---- DMA-stage A group: chunk c = tap*6 + (dhalf*3+dt), 1KB each ----
        auto stageA = [&](int tapLo, int bufOff) {
            const int rem  = NT - tapLo;
            const int nch  = (rem < 3 ? rem : 3) * 6;
            const unsigned short* gq = wpack
                + (size_t)(TBASE + tapLo) * 15360 + (size_t)q * 3072 + laneAsrc;
            for (int c = wid; c < nch; c += 8) {
                const int tapIdx = c / 6;
                const int r = c - tapIdx * 6;
                const unsigned short* g = gq + (size_t)tapIdx * 15360 + r * 512;
                __builtin_amdgcn_global_load_lds(
                    (const __attribute__((address_space(1))) unsigned int*)g,
                    (__attribute__((address_space(3))) unsigned int*)(AbufRaw + bufOff + c * 1024),
                    16, 0, 0);
            }
        };

        stageA(0, 0);          // prologue: group 0 -> buf 0
        __syncthreads();       // patch + A group 0 visible

        for (int tg = 0; tg < NG; ++tg) {
            if (tg + 1 < NG) stageA((tg + 1) * 3, ((tg + 1) & 1) * ABUF_HALF);

            // ---- compute group tg from buf[tg&1] ----
            const unsigned char* Ab = AbufRaw + (tg & 1) * ABUF_HALF;
            const int tapLo = tg * 3;
            const int rem = NT - tapLo;
            const int ntap = rem < 3 ? rem : 3;
            #pragma unroll 1
            for (int ti = 0; ti < ntap; ++ti) {
                const int tt = tapLo + ti;
                const int kh = tt / KSZ, kw = tt - kh * KSZ;
                const unsigned char* Abase = Ab + (ti * 6 + dhalf * 3) * 1024 + lane * 16;
                const v8s A0 = *(const v8s*)(Abase);
                const v8s A1 = *(const v8s*)(Abase + 1024);
                const v8s A2 = *(const v8s*)(Abase + 2048);
                const int rb0 = (ptb + kh) * PXR;
                v8s Bv[4];
                #pragma unroll
                for (int pp = 0; pp < 4; ++pp)
                    Bv[pp] = *(const v8s*)(patchB + (rb0 + pp * PXR + kw) * PIXSTRIDE + laneBoff);
                #pragma unroll
                for (int pp = 0; pp < 4; ++pp) {
                    acc[0][pp] = __builtin_amdgcn_mfma_f32_16x16x32_bf16(A0, Bv[pp], acc[0][pp], 0, 0, 0);
                    acc[1][pp] = __builtin_amdgcn_mfma_f32_16x16x32_bf16(A1, Bv[pp], acc[1][pp], 0, 0, 0);
                    acc[2][pp] = __builtin_amdgcn_mfma_f32_16x16x32_bf16(A2, Bv[pp], acc[2][pp], 0, 0, 0);
                }
            }
            __syncthreads();   // drains next group's DMA (covered by the 36 MFMAs above)
        }
    }

    // ---- epilogue (round-7/14 verbatim) ----
    #pragma unroll
    for (int dt = 0; dt < 3; ++dt) {
        #pragma unroll
        for (int reg = 0; reg < 4; ++reg) {
            const int d = dhalf * 48 + dt * 16 + hi * 4 + reg;
            const float iv = bns[d*2+0], cv = bns[d*2+1];
            unsigned short* pl = (unsigned short*)(outp + (((size_t)b * D_ + d) << 12));
            #pragma unroll
            for (int pp = 0; pp < 4; ++pp) {
                const float y = fmaxf(0.f, fmaf(acc[dt][pp][reg], iv, cv));
                const int idx = ((h0 + ptb + pp) << 6) + w0 + lo;
                if constexpr (MODE == 0) {
                    pl[4096 + idx] = f2bf(y);
                } else if constexpr (MODE == 1) {
                    pl[idx] = f2bf(y);
                } else {
                    const float y2 = bf2f(pl[idx]);
                    const float y3 = bf2f(pl[4096 + idx]);
                    const float av = y + y2 + y3;
                    const float mv = fmaxf(y, fmaxf(y2, y3));
                    pl[idx]        = f2bf(av);
                    pl[4096 + idx] = f2bf(mv);
                }
            }
        }
    }
}

// ---------------------------------------------------------------------------
// Kernel B: per-plane 3x3 conv over [add; max] with avg folded (unchanged).
// ---------------------------------------------------------------------------
__global__ __launch_bounds__(256) void fuse_kernel(
    const float* __restrict__ wf, float* __restrict__ out)
{
    const int p = blockIdx.x;      // plane = b*96 + d
    const int t = threadIdx.x;
    __shared__ float sa[66 * 66];
    __shared__ float sm[66 * 66];
    const bf16* base = (const bf16*)(out + ((size_t)p << 12));

    for (int i = t; i < 66 * 66; i += 256) {
        const int c = i % 66, r = i / 66;
        const int gh = r - 1, gw = c - 1;
        float va = 0.f, vm = 0.f;
        if (gh >= 0 && gh < 64 && gw >= 0 && gw < 64) {
            va = __bfloat162float(base[(gh << 6) + gw]);
            vm = __bfloat162float(base[4096 + (gh << 6) + gw]);
        }
        sa[i] = va; sm[i] = vm;
    }

    float wa[9], wm[9];
    #pragma unroll
    for (int j = 0; j < 9; ++j) {
        wa[j] = wf[j] + wf[9 + j] * (1.f / 3.f);
        wm[j] = wf[18 + j];
    }
    __syncthreads();

    float* op = out + ((size_t)p << 12);
    for (int i = t; i < 4096; i += 256) {
        const int h = i >> 6, w = i & 63;
        float acc = 0.f;
        #pragma unroll
        for (int kh = 0; kh < 3; ++kh) {
            #pragma unroll
            for (int kw = 0; kw < 3; ++kw) {
                acc = fmaf(sa[(h + kh) * 66 + (w + kw)], wa[kh * 3 + kw], acc);
                acc = fmaf(sm[(h + kh) * 66 + (w + kw)], wm[kh * 3 + kw], acc);
            }
        }
        op[i] = acc;
    }
}

extern "C" void kernel_launch(void* const* d_in, const int* in_sizes, int n_in,
                              void* d_out, int out_size, void* d_ws, size_t ws_size,
                              hipStream_t stream)
{
    const float* x   = (const float*)d_in[0];
    const float* w1  = (const float*)d_in[1];
    const float* b1  = (const float*)d_in[2];
    const float* g1  = (const float*)d_in[3];
    const float* be1 = (const float*)d_in[4];
    const float* m1  = (const float*)d_in[5];
    const float* v1  = (const float*)d_in[6];
    const float* w2  = (const float*)d_in[7];
    const float* b2  = (const float*)d_in[8];
    const float* g2  = (const float*)d_in[9];
    const float* be2 = (const float*)d_in[10];
    const float* m2  = (const float*)d_in[11];
    const float* v2  = (const float*)d_in[12];
    const float* w3  = (const float*)d_in[13];
    const float* b3  = (const float*)d_in[14];
    const float* g3  = (const float*)d_in[15];
    const float* be3 = (const float*)d_in[16];
    const float* m3  = (const float*)d_in[17];
    const float* v3  = (const float*)d_in[18];
    const float* wf  = (const float*)d_in[19];
    float* out = (float*)d_out;

    // d_ws: packed bf16 weights only (2.55 MB, proven safe rounds 4-18)
    unsigned short* wpack = (unsigned short*)d_ws;

    prep_weights<<<(WPACK_ELEMS + 255) / 256, 256, 0, stream>>>(w1, w2, w3, wpack);

    dim3 gridA(16, B_);   // 16 spatial tiles x 32 batch
    conv_branch<7, 0, 0><<<gridA, 512, 0, stream>>>(x, wpack, b3, g3, be3, m3, v3, out);
    conv_branch<5, 49, 1><<<gridA, 512, 0, stream>>>(x, wpack, b2, g2, be2, m2, v2, out);
    conv_branch<3, 74, 2><<<gridA, 512, 0, stream>>>(x, wpack, b1, g1, be1, m1, v1, out);

    fuse_kernel<<<B_ * D_, 256, 0, stream>>>(wf, out);
}